// Round 14
// baseline (185.059 us; speedup 1.0000x reference)
//
#include <hip/hip_runtime.h>
#include <hip/hip_fp16.h>

#define KDIM 1024
#define DDIM 64
#define SPAT 32768
#define NVEC 65536
#define DSP  (DDIM * SPAT)          // 2097152
#define ROWS 32                     // z-rows per block
#define MARGIN_ACC 0.25f            // acc-space (= 512*dist ~ 4.9e-4); validated R13 pass
#define ZPAD 65                     // odd stride -> conflict-free LDS rows
#define QCAP 320

typedef _Float16 half8 __attribute__((ext_vector_type(8)));
typedef float floatx4 __attribute__((ext_vector_type(4)));

__device__ __forceinline__ float opaque(float x) { asm volatile("" : "+v"(x)); return x; }

// sortable-uint transform for signed floats (monotone increasing)
__device__ __forceinline__ unsigned int f2s(float x) {
    unsigned int u = __float_as_uint(x);
    return u ^ ((u >> 31) ? 0xffffffffu : 0x80000000u);
}
__device__ __forceinline__ float s2f(unsigned int u) {
    unsigned int v = u ^ ((u & 0x80000000u) ? 0x80000000u : 0xffffffffu);
    return __uint_as_float(v);
}

// Bitwise replica of np.add.reduce pairwise base case over fl(x[d]^2), d=0..63 (R3-proven)
__device__ __forceinline__ float np_sumsq64(const float* x) {
    float r8[8];
#pragma unroll
    for (int j = 0; j < 8; ++j) r8[j] = opaque(x[1 + j] * x[1 + j]);
#pragma unroll
    for (int i = 8; i < 56; i += 8) {
#pragma unroll
        for (int j = 0; j < 8; ++j) r8[j] += opaque(x[1 + i + j] * x[1 + i + j]);
    }
    float res = ((r8[0] + r8[1]) + (r8[2] + r8[3])) + ((r8[4] + r8[5]) + (r8[6] + r8[7]));
#pragma unroll
    for (int m = 57; m < 64; ++m) res += opaque(x[m] * x[m]);
    return opaque(x[0] * x[0]) + res;
}

// Bit-exact numpy-f32 distance, packed (distbits<<32)|k. fl(2e)*z inside fma == sgemm's (2z).e
__device__ __forceinline__ unsigned long long exact_score(
    const float* zr, float snr, const float* __restrict__ emb,
    const float* __restrict__ h_, int k)
{
    const float* ep = emb + (size_t)k * DDIM;
    float acc = 0.f;
#pragma unroll
    for (int d = 0; d < DDIM; ++d)
        acc = fmaf(2.0f * ep[d], zr[d], acc);  // sequential f32 FMA from 0, ascending d
    float tt   = snr + h_[k];                  // fl(sn + h)
    float dist = tt - acc;                     // fl(t - 2 z.e)
    return ((unsigned long long)__float_as_uint(dist) << 32) | (unsigned int)k;
}

// K1 (64 blocks x 16 k-rows): eh = fp16(e*1024); h = ||e||^2 (np-f32); hneg = -512*h; loss = 0
__global__ void vq_prep_e(const float* __restrict__ emb, float* __restrict__ h,
                          float* __restrict__ hneg, __half* __restrict__ eh,
                          float* __restrict__ loss) {
    const int tid = threadIdx.x;
    const int kbase = blockIdx.x * 16;
#pragma unroll
    for (int i = 0; i < 4; ++i) {
        int g = i * 256 + tid;
        float v = emb[(size_t)kbase * DDIM + g];
        eh[(size_t)kbase * DDIM + g] = (__half)(_Float16)(v * 1024.0f);
    }
    if (tid < 16) {
        float s = np_sumsq64(emb + (size_t)(kbase + tid) * DDIM);
        h[kbase + tid]    = s;
        hneg[kbase + tid] = -512.0f * s;
    }
    if (blockIdx.x == 0 && tid == 0) *loss = 0.f;
}

// K2: 32 rows/block, grid 2048 -> 8 blocks/CU. Two-pass MFMA (h in C), rescore, epilogue.
__global__ __launch_bounds__(256, 8) void vq_mfma_kernel(
    const float* __restrict__ z, const float* __restrict__ emb,
    const __half* __restrict__ eh_, const float* __restrict__ h_,
    const float* __restrict__ hneg_, float* __restrict__ out,
    float* __restrict__ loss, float* __restrict__ idxf)
{
    __shared__ float zrow[ROWS * ZPAD];          // 8.3 KB
    __shared__ float lds_sn[ROWS];
    __shared__ unsigned int m1bits[ROWS];        // sortable-uint row max (acc space)
    __shared__ int qcnt;
    __shared__ unsigned short qk[QCAP];
    __shared__ unsigned char  qn[QCAP];
    __shared__ unsigned long long rbest[ROWS];

    const int tid = threadIdx.x, l = tid & 63, w = tid >> 6;
    const int nbase = blockIdx.x * ROWS;
    const int b = nbase >> 15, s0 = nbase & (SPAT - 1);
    const int col16 = l & 15, g16 = l >> 4;
    const float* zbase = z + (size_t)b * DSP + s0;

    if (tid == 0) qcnt = 0;
    if (tid < ROWS) { rbest[tid] = ~0ull; m1bits[tid] = 0u; }

    // stage 32 z-rows x 64 planes: 2048 floats, 8 per thread, coalesced 128B groups
#pragma unroll
    for (int j = 0; j < 8; ++j) {
        const int g = j * 256 + tid;
        const int d = g >> 5, r = g & 31;
        zrow[r * ZPAD + d] = zbase[(size_t)d * SPAT + r];
    }
    __syncthreads();

    if (tid < ROWS) lds_sn[tid] = np_sumsq64(&zrow[tid * ZPAD]);

    // resident Z hi fragments: 2 row-groups x 2 k-passes = 16 VGPR
    half8 zf[2][2];
#pragma unroll
    for (int nc = 0; nc < 2; ++nc) {
        const int r = nc * 16 + col16;
#pragma unroll
        for (int kp = 0; kp < 2; ++kp) {
            const int d0 = g16 * 8 + kp * 32;
            half8 vh;
#pragma unroll
            for (int u = 0; u < 8; ++u)
                vh[u] = (_Float16)zrow[r * ZPAD + d0 + u];
            zf[nc][kp] = vh;
        }
    }

    const int myk0 = w * 256;
    // R9-style spill-free 1-deep prefetch: current copy + next in flight
    half8 ef0, ef1; floatx4 hc;
#define LOADT(t) { \
        const size_t o_ = (size_t)(myk0 + (t) * 16 + col16) * DDIM + g16 * 8; \
        ef0 = *(const half8*)(eh_ + o_); \
        ef1 = *(const half8*)(eh_ + o_ + 32); \
        hc  = *(const floatx4*)(hneg_ + myk0 + (t) * 16 + g16 * 4); }

    // ---- pass 1: approx row MAX of acc (= -512*dist), 1-deep prefetch ----
    float m1[2] = {-3.0e38f, -3.0e38f};
    LOADT(0)
#pragma unroll
    for (int t = 0; t < 16; ++t) {
        half8 cf0 = ef0, cf1 = ef1; floatx4 chc = hc;
        if (t < 15) LOADT(t + 1)
#pragma unroll
        for (int nc = 0; nc < 2; ++nc) {
            floatx4 acc = __builtin_amdgcn_mfma_f32_16x16x32_f16(cf0, zf[nc][0], chc, 0, 0, 0);
            acc = __builtin_amdgcn_mfma_f32_16x16x32_f16(cf1, zf[nc][1], acc, 0, 0, 0);
            m1[nc] = fmaxf(m1[nc], fmaxf(fmaxf(acc[0], acc[1]), fmaxf(acc[2], acc[3])));
        }
    }
#pragma unroll
    for (int nc = 0; nc < 2; ++nc)
        atomicMax(&m1bits[nc * 16 + col16], f2s(m1[nc]));
    __syncthreads();

    float thr[2];
#pragma unroll
    for (int nc = 0; nc < 2; ++nc) thr[nc] = s2f(m1bits[nc * 16 + col16]) - MARGIN_ACC;

    // ---- pass 2: re-scan, push candidates with acc >= rowmax - MARGIN ----
    LOADT(0)
#pragma unroll
    for (int t = 0; t < 16; ++t) {
        half8 cf0 = ef0, cf1 = ef1; floatx4 chc = hc;
        if (t < 15) LOADT(t + 1)
        const int rbase = myk0 + t * 16 + g16 * 4;
#pragma unroll
        for (int nc = 0; nc < 2; ++nc) {
            floatx4 acc = __builtin_amdgcn_mfma_f32_16x16x32_f16(cf0, zf[nc][0], chc, 0, 0, 0);
            acc = __builtin_amdgcn_mfma_f32_16x16x32_f16(cf1, zf[nc][1], acc, 0, 0, 0);
#pragma unroll
            for (int j = 0; j < 4; ++j) {
                if (acc[j] >= thr[nc]) {
                    int p = atomicAdd(&qcnt, 1);
                    if (p < QCAP) {
                        qk[p] = (unsigned short)(rbase + j);
                        qn[p] = (unsigned char)(nc * 16 + col16);
                    }
                }
            }
        }
    }
#undef LOADT
    __syncthreads();

    // ---- phase 3: bit-exact numpy-f32 rescore of candidates ----
    const int qlen = min(qcnt, QCAP);
    for (int i = tid; i < qlen; i += 256) {
        const int r = qn[i];
        atomicMin(&rbest[r], exact_score(&zrow[r * ZPAD], lds_sn[r], emb, h_, qk[i]));
    }
    __syncthreads();

    if (qcnt > QCAP) {   // cold correctness fallback: full exact scan (8 threads per row)
        const int row = tid & 31, kq = tid >> 5;
        for (int k = kq * 128; k < kq * 128 + 128; ++k)
            atomicMin(&rbest[row], exact_score(&zrow[row * ZPAD], lds_sn[row], emb, h_, k));
        __syncthreads();
    }

    // ---- epilogue: idx, z_q gather, loss. lane = (row | plane-half), coalesced 128B ----
    if (tid < ROWS) idxf[nbase + tid] = (float)(unsigned int)(rbest[tid] & 0xffffffffu);
    {
        const int r = l & 31;                    // row
        const int dh = (l >> 5) * 8;             // plane sub-block 0/8
        const int I1 = (int)(rbest[r] & 0xffffffffu);
        const int dbase = w * 16 + dh;
        float* opb = out + (size_t)b * DSP + s0;
        float lsum = 0.f;
#pragma unroll
        for (int j = 0; j < 8; ++j) {
            const int d = dbase + j;
            float qv = emb[(size_t)I1 * DDIM + d];
            opb[(size_t)d * SPAT + r] = qv;
            float df = qv - zrow[r * ZPAD + d];
            lsum = fmaf(df, df, lsum);
        }
#pragma unroll
        for (int off = 32; off > 0; off >>= 1)
            lsum += __shfl_down(lsum, off, 64);
        if (l == 0)
            atomicAdd(loss, lsum * (1.25f / 4194304.0f));  // (beta+1)*mean
    }
}

extern "C" void kernel_launch(void* const* d_in, const int* in_sizes, int n_in,
                              void* d_out, int out_size, void* d_ws, size_t ws_size,
                              hipStream_t stream) {
    const float* z   = (const float*)d_in[0];   // [2, 64, 32, 32, 32]
    const float* emb = (const float*)d_in[1];   // [1024, 64]
    float* out  = (float*)d_out;                // z_q (4194304) | loss (1) | indices (65536)
    float* loss = out + 4194304;
    float* idxf = out + 4194305;

    float* h_    = (float*)d_ws;                // [1024]
    float* hneg_ = h_ + KDIM;                   // [1024]
    __half* eh_  = (__half*)(hneg_ + KDIM);     // [1024*64] halves

    vq_prep_e<<<KDIM / 16, 256, 0, stream>>>(emb, h_, hneg_, eh_, loss);
    vq_mfma_kernel<<<NVEC / ROWS, 256, 0, stream>>>(z, emb, eh_, h_, hneg_, out, loss, idxf);
}

// Round 15
// 150.312 us; speedup vs baseline: 1.2312x; 1.2312x over previous
//
#include <hip/hip_runtime.h>
#include <hip/hip_fp16.h>

#define KDIM 1024
#define DDIM 64
#define SPAT 32768
#define NVEC 65536
#define DSP  (DDIM * SPAT)          // 2097152
#define ROWS 32                     // z-rows per block
#define MARGIN_ACC 0.25f            // acc-space (= 512*dist ~ 4.9e-4); validated R13 pass
#define ZPAD 65                     // odd stride -> conflict-free LDS rows
#define QCAP 320

typedef _Float16 half8 __attribute__((ext_vector_type(8)));
typedef float floatx4 __attribute__((ext_vector_type(4)));

__device__ __forceinline__ float opaque(float x) { asm volatile("" : "+v"(x)); return x; }

// sortable-uint transform for signed floats (monotone increasing)
__device__ __forceinline__ unsigned int f2s(float x) {
    unsigned int u = __float_as_uint(x);
    return u ^ ((u >> 31) ? 0xffffffffu : 0x80000000u);
}
__device__ __forceinline__ float s2f(unsigned int u) {
    unsigned int v = u ^ ((u & 0x80000000u) ? 0x80000000u : 0xffffffffu);
    return __uint_as_float(v);
}

// Bitwise replica of np.add.reduce pairwise base case over fl(x[d]^2), d=0..63 (R3-proven)
__device__ __forceinline__ float np_sumsq64(const float* x) {
    float r8[8];
#pragma unroll
    for (int j = 0; j < 8; ++j) r8[j] = opaque(x[1 + j] * x[1 + j]);
#pragma unroll
    for (int i = 8; i < 56; i += 8) {
#pragma unroll
        for (int j = 0; j < 8; ++j) r8[j] += opaque(x[1 + i + j] * x[1 + i + j]);
    }
    float res = ((r8[0] + r8[1]) + (r8[2] + r8[3])) + ((r8[4] + r8[5]) + (r8[6] + r8[7]));
#pragma unroll
    for (int m = 57; m < 64; ++m) res += opaque(x[m] * x[m]);
    return opaque(x[0] * x[0]) + res;
}

// Bit-exact numpy-f32 distance, packed (distbits<<32)|k. fl(2e)*z inside fma == sgemm's (2z).e
__device__ __forceinline__ unsigned long long exact_score(
    const float* zr, float snr, const float* __restrict__ emb,
    const float* __restrict__ h_, int k)
{
    const float* ep = emb + (size_t)k * DDIM;
    float acc = 0.f;
#pragma unroll
    for (int d = 0; d < DDIM; ++d)
        acc = fmaf(2.0f * ep[d], zr[d], acc);  // sequential f32 FMA from 0, ascending d
    float tt   = snr + h_[k];                  // fl(sn + h)
    float dist = tt - acc;                     // fl(t - 2 z.e)
    return ((unsigned long long)__float_as_uint(dist) << 32) | (unsigned int)k;
}

// K1 (64 blocks x 16 k-rows): eh = fp16(e*1024); h = ||e||^2 (np-f32); hneg = -512*h; loss = 0
__global__ void vq_prep_e(const float* __restrict__ emb, float* __restrict__ h,
                          float* __restrict__ hneg, __half* __restrict__ eh,
                          float* __restrict__ loss) {
    const int tid = threadIdx.x;
    const int kbase = blockIdx.x * 16;
#pragma unroll
    for (int i = 0; i < 4; ++i) {
        int g = i * 256 + tid;
        float v = emb[(size_t)kbase * DDIM + g];
        eh[(size_t)kbase * DDIM + g] = (__half)(_Float16)(v * 1024.0f);
    }
    if (tid < 16) {
        float s = np_sumsq64(emb + (size_t)(kbase + tid) * DDIM);
        h[kbase + tid]    = s;
        hneg[kbase + tid] = -512.0f * s;
    }
    if (blockIdx.x == 0 && tid == 0) *loss = 0.f;
}

// K2: 32 rows/block, grid 2048 -> 8 blocks/CU at runtime. Compiler target stays 4 waves/EU
// (64 VGPR, spill-free); occupancy comes from the grid, NOT the launch_bounds arg (R14 lesson).
__global__ __launch_bounds__(256, 4) void vq_mfma_kernel(
    const float* __restrict__ z, const float* __restrict__ emb,
    const __half* __restrict__ eh_, const float* __restrict__ h_,
    const float* __restrict__ hneg_, float* __restrict__ out,
    float* __restrict__ loss, float* __restrict__ idxf)
{
    __shared__ float zrow[ROWS * ZPAD];          // 8.3 KB
    __shared__ float lds_sn[ROWS];
    __shared__ unsigned int m1bits[ROWS];        // sortable-uint row max (acc space)
    __shared__ int qcnt;
    __shared__ unsigned short qk[QCAP];
    __shared__ unsigned char  qn[QCAP];
    __shared__ unsigned long long rbest[ROWS];

    const int tid = threadIdx.x, l = tid & 63, w = tid >> 6;
    const int nbase = blockIdx.x * ROWS;
    const int b = nbase >> 15, s0 = nbase & (SPAT - 1);
    const int col16 = l & 15, g16 = l >> 4;
    const float* zbase = z + (size_t)b * DSP + s0;

    if (tid == 0) qcnt = 0;
    if (tid < ROWS) { rbest[tid] = ~0ull; m1bits[tid] = 0u; }

    // stage 32 z-rows x 64 planes: 2048 floats, 8 per thread, coalesced 128B groups
#pragma unroll
    for (int j = 0; j < 8; ++j) {
        const int g = j * 256 + tid;
        const int d = g >> 5, r = g & 31;
        zrow[r * ZPAD + d] = zbase[(size_t)d * SPAT + r];
    }
    __syncthreads();

    if (tid < ROWS) lds_sn[tid] = np_sumsq64(&zrow[tid * ZPAD]);

    // resident Z hi fragments: 2 row-groups x 2 k-passes = 16 VGPR
    half8 zf[2][2];
#pragma unroll
    for (int nc = 0; nc < 2; ++nc) {
        const int r = nc * 16 + col16;
#pragma unroll
        for (int kp = 0; kp < 2; ++kp) {
            const int d0 = g16 * 8 + kp * 32;
            half8 vh;
#pragma unroll
            for (int u = 0; u < 8; ++u)
                vh[u] = (_Float16)zrow[r * ZPAD + d0 + u];
            zf[nc][kp] = vh;
        }
    }

    const int myk0 = w * 256;
    // R9-style spill-free 1-deep prefetch: current copy + next in flight
    half8 ef0, ef1; floatx4 hc;
#define LOADT(t) { \
        const size_t o_ = (size_t)(myk0 + (t) * 16 + col16) * DDIM + g16 * 8; \
        ef0 = *(const half8*)(eh_ + o_); \
        ef1 = *(const half8*)(eh_ + o_ + 32); \
        hc  = *(const floatx4*)(hneg_ + myk0 + (t) * 16 + g16 * 4); }

    // ---- pass 1: approx row MAX of acc (= -512*dist), 1-deep prefetch ----
    float m1[2] = {-3.0e38f, -3.0e38f};
    LOADT(0)
#pragma unroll
    for (int t = 0; t < 16; ++t) {
        half8 cf0 = ef0, cf1 = ef1; floatx4 chc = hc;
        if (t < 15) LOADT(t + 1)
#pragma unroll
        for (int nc = 0; nc < 2; ++nc) {
            floatx4 acc = __builtin_amdgcn_mfma_f32_16x16x32_f16(cf0, zf[nc][0], chc, 0, 0, 0);
            acc = __builtin_amdgcn_mfma_f32_16x16x32_f16(cf1, zf[nc][1], acc, 0, 0, 0);
            m1[nc] = fmaxf(m1[nc], fmaxf(fmaxf(acc[0], acc[1]), fmaxf(acc[2], acc[3])));
        }
    }
#pragma unroll
    for (int nc = 0; nc < 2; ++nc)
        atomicMax(&m1bits[nc * 16 + col16], f2s(m1[nc]));
    __syncthreads();

    float thr[2];
#pragma unroll
    for (int nc = 0; nc < 2; ++nc) thr[nc] = s2f(m1bits[nc * 16 + col16]) - MARGIN_ACC;

    // ---- pass 2: re-scan, push candidates with acc >= rowmax - MARGIN ----
    LOADT(0)
#pragma unroll
    for (int t = 0; t < 16; ++t) {
        half8 cf0 = ef0, cf1 = ef1; floatx4 chc = hc;
        if (t < 15) LOADT(t + 1)
        const int rbase = myk0 + t * 16 + g16 * 4;
#pragma unroll
        for (int nc = 0; nc < 2; ++nc) {
            floatx4 acc = __builtin_amdgcn_mfma_f32_16x16x32_f16(cf0, zf[nc][0], chc, 0, 0, 0);
            acc = __builtin_amdgcn_mfma_f32_16x16x32_f16(cf1, zf[nc][1], acc, 0, 0, 0);
#pragma unroll
            for (int j = 0; j < 4; ++j) {
                if (acc[j] >= thr[nc]) {
                    int p = atomicAdd(&qcnt, 1);
                    if (p < QCAP) {
                        qk[p] = (unsigned short)(rbase + j);
                        qn[p] = (unsigned char)(nc * 16 + col16);
                    }
                }
            }
        }
    }
#undef LOADT
    __syncthreads();

    // ---- phase 3: bit-exact numpy-f32 rescore of candidates ----
    const int qlen = min(qcnt, QCAP);
    for (int i = tid; i < qlen; i += 256) {
        const int r = qn[i];
        atomicMin(&rbest[r], exact_score(&zrow[r * ZPAD], lds_sn[r], emb, h_, qk[i]));
    }
    __syncthreads();

    if (qcnt > QCAP) {   // cold correctness fallback: full exact scan (8 threads per row)
        const int row = tid & 31, kq = tid >> 5;
        for (int k = kq * 128; k < kq * 128 + 128; ++k)
            atomicMin(&rbest[row], exact_score(&zrow[row * ZPAD], lds_sn[row], emb, h_, k));
        __syncthreads();
    }

    // ---- epilogue: idx, z_q gather, loss. lane = (row | plane-half), coalesced 128B ----
    if (tid < ROWS) idxf[nbase + tid] = (float)(unsigned int)(rbest[tid] & 0xffffffffu);
    {
        const int r = l & 31;                    // row
        const int dh = (l >> 5) * 8;             // plane sub-block 0/8
        const int I1 = (int)(rbest[r] & 0xffffffffu);
        const int dbase = w * 16 + dh;
        float* opb = out + (size_t)b * DSP + s0;
        float lsum = 0.f;
#pragma unroll
        for (int j = 0; j < 8; ++j) {
            const int d = dbase + j;
            float qv = emb[(size_t)I1 * DDIM + d];
            opb[(size_t)d * SPAT + r] = qv;
            float df = qv - zrow[r * ZPAD + d];
            lsum = fmaf(df, df, lsum);
        }
#pragma unroll
        for (int off = 32; off > 0; off >>= 1)
            lsum += __shfl_down(lsum, off, 64);
        if (l == 0)
            atomicAdd(loss, lsum * (1.25f / 4194304.0f));  // (beta+1)*mean
    }
}

extern "C" void kernel_launch(void* const* d_in, const int* in_sizes, int n_in,
                              void* d_out, int out_size, void* d_ws, size_t ws_size,
                              hipStream_t stream) {
    const float* z   = (const float*)d_in[0];   // [2, 64, 32, 32, 32]
    const float* emb = (const float*)d_in[1];   // [1024, 64]
    float* out  = (float*)d_out;                // z_q (4194304) | loss (1) | indices (65536)
    float* loss = out + 4194304;
    float* idxf = out + 4194305;

    float* h_    = (float*)d_ws;                // [1024]
    float* hneg_ = h_ + KDIM;                   // [1024]
    __half* eh_  = (__half*)(hneg_ + KDIM);     // [1024*64] halves

    vq_prep_e<<<KDIM / 16, 256, 0, stream>>>(emb, h_, hneg_, eh_, loss);
    vq_mfma_kernel<<<NVEC / ROWS, 256, 0, stream>>>(z, emb, eh_, h_, hneg_, out, loss, idxf);
}

// Round 16
// 85.357 us; speedup vs baseline: 2.1681x; 1.7610x over previous
//
#include <hip/hip_runtime.h>
#include <hip/hip_fp16.h>

#define KDIM 1024
#define DDIM 64
#define SPAT 32768
#define NVEC 65536
#define DSP  (DDIM * SPAT)          // 2097152
#define ROWS 64                     // z-rows per block
#define MARGIN_ACC 0.25f            // biased-acc space (= 512*dist ~ 4.9e-4); validated R13/R15
#define ZPAD 65                     // odd stride -> conflict-free LDS rows
#define QCAP 768

typedef _Float16 half8 __attribute__((ext_vector_type(8)));
typedef float floatx4 __attribute__((ext_vector_type(4)));

__device__ __forceinline__ float opaque(float x) { asm volatile("" : "+v"(x)); return x; }

// Bitwise replica of np.add.reduce pairwise base case over fl(x[d]^2), d=0..63 (R3-proven)
__device__ __forceinline__ float np_sumsq64(const float* x) {
    float r8[8];
#pragma unroll
    for (int j = 0; j < 8; ++j) r8[j] = opaque(x[1 + j] * x[1 + j]);
#pragma unroll
    for (int i = 8; i < 56; i += 8) {
#pragma unroll
        for (int j = 0; j < 8; ++j) r8[j] += opaque(x[1 + i + j] * x[1 + i + j]);
    }
    float res = ((r8[0] + r8[1]) + (r8[2] + r8[3])) + ((r8[4] + r8[5]) + (r8[6] + r8[7]));
#pragma unroll
    for (int m = 57; m < 64; ++m) res += opaque(x[m] * x[m]);
    return opaque(x[0] * x[0]) + res;
}

// Bit-exact numpy-f32 distance, packed (distbits<<32)|k. fl(2e)*z inside fma == sgemm's (2z).e
__device__ __forceinline__ unsigned long long exact_score(
    const float* zr, float snr, const float* __restrict__ emb,
    const float* __restrict__ h_, int k)
{
    const float* ep = emb + (size_t)k * DDIM;
    float acc = 0.f;
#pragma unroll
    for (int d = 0; d < DDIM; ++d)
        acc = fmaf(2.0f * ep[d], zr[d], acc);  // sequential f32 FMA from 0, ascending d
    float tt   = snr + h_[k];                  // fl(sn + h)
    float dist = tt - acc;                     // fl(t - 2 z.e)
    return ((unsigned long long)__float_as_uint(dist) << 32) | (unsigned int)k;
}

// K1 (64 blocks x 16 k-rows): ehn = fp16(-1024e); h = ||e||^2 (np-f32); hp = +512h; loss = 0
__global__ void vq_prep_e(const float* __restrict__ emb, float* __restrict__ h,
                          float* __restrict__ hp, __half* __restrict__ ehn,
                          float* __restrict__ loss) {
    const int tid = threadIdx.x;
    const int kbase = blockIdx.x * 16;
#pragma unroll
    for (int i = 0; i < 4; ++i) {
        int g = i * 256 + tid;
        float v = emb[(size_t)kbase * DDIM + g];
        ehn[(size_t)kbase * DDIM + g] = (__half)(_Float16)(v * -1024.0f);
    }
    if (tid < 16) {
        float s = np_sumsq64(emb + (size_t)(kbase + tid) * DDIM);
        h[kbase + tid]  = s;
        hp[kbase + tid] = 512.0f * s;
    }
    if (blockIdx.x == 0 && tid == 0) *loss = 0.f;
}

// K2: SINGLE MFMA pass, per-scanner packed top-2, reduce+push, exact rescore, epilogue.
// acc = mfma(fp16(-1024e), fp16(z), C=512h) = 512*(h - 2 z.e) => min acc = min dist (sans sn).
__global__ __launch_bounds__(256, 4) void vq_mfma_kernel(
    const float* __restrict__ z, const float* __restrict__ emb,
    const __half* __restrict__ ehn_, const float* __restrict__ h_,
    const float* __restrict__ hp_, float* __restrict__ out,
    float* __restrict__ loss, float* __restrict__ idxf)
{
    __shared__ float zrow[ROWS * ZPAD];          // 16.6 KB
    __shared__ float lds_sn[ROWS];
    __shared__ float lds_hp[KDIM];               // 4 KB
    __shared__ unsigned int sc[16][ROWS][2];     // 8 KB: per-scanner packed top-2
    __shared__ int qcnt;
    __shared__ unsigned short qk[QCAP];
    __shared__ unsigned char  qn[QCAP];
    __shared__ unsigned long long rbest[ROWS];

    const int tid = threadIdx.x, l = tid & 63, w = tid >> 6;
    const int nbase = blockIdx.x * ROWS;
    const int b = nbase >> 15, s0 = nbase & (SPAT - 1);
    const int col16 = l & 15, g16 = l >> 4;
    const float* zbase = z + (size_t)b * DSP + s0;

    if (tid == 0) qcnt = 0;
    if (tid < ROWS) rbest[tid] = ~0ull;

    // stage hp (coalesced float4) and 64 z-rows (coalesced 256B groups)
    ((float4*)lds_hp)[tid] = ((const float4*)hp_)[tid];
#pragma unroll
    for (int j = 0; j < 16; ++j) {
        const int g = j * 256 + tid;
        const int d = g >> 6, r = g & 63;
        zrow[r * ZPAD + d] = zbase[(size_t)d * SPAT + r];
    }
    __syncthreads();

    if (tid < ROWS) lds_sn[tid] = np_sumsq64(&zrow[tid * ZPAD]);

    // resident Z fragments: 4 row-groups x 2 k-passes = 32 VGPR
    half8 zf[4][2];
#pragma unroll
    for (int nc = 0; nc < 4; ++nc) {
        const int r = nc * 16 + col16;
#pragma unroll
        for (int kp = 0; kp < 2; ++kp) {
            const int d0 = g16 * 8 + kp * 32;
            half8 vh;
#pragma unroll
            for (int u = 0; u < 8; ++u)
                vh[u] = (_Float16)zrow[r * ZPAD + d0 + u];
            zf[nc][kp] = vh;
        }
    }

    const int myk0 = w * 256;
    unsigned int b1[4], b2[4];
#pragma unroll
    for (int nc = 0; nc < 4; ++nc) { b1[nc] = 0xffffffffu; b2[nc] = 0xffffffffu; }

    half8 ef0, ef1;
#define LOADE(t) { \
        const size_t o_ = (size_t)(myk0 + (t) * 16 + col16) * DDIM + g16 * 8; \
        ef0 = *(const half8*)(ehn_ + o_); \
        ef1 = *(const half8*)(ehn_ + o_ + 32); }

    // ---- single pass: MFMA + packed top-2 insert ----
    LOADE(0)
#pragma unroll
    for (int t = 0; t < 16; ++t) {
        half8 cf0 = ef0, cf1 = ef1;
        if (t < 15) LOADE(t + 1)
        floatx4 hcv = *(const floatx4*)(&lds_hp[myk0 + t * 16 + g16 * 4]);
#pragma unroll
        for (int nc = 0; nc < 4; ++nc) {
            floatx4 acc = __builtin_amdgcn_mfma_f32_16x16x32_f16(cf0, zf[nc][0], hcv, 0, 0, 0);
            acc = __builtin_amdgcn_mfma_f32_16x16x32_f16(cf1, zf[nc][1], acc, 0, 0, 0);
#pragma unroll
            for (int j = 0; j < 4; ++j) {
                // biased-monotone pack: acc in (-104,104) -> acc+512 > 0, bits ordered
                unsigned int p = (__float_as_uint(acc[j] + 512.0f) & 0xffffffc0u)
                               | (unsigned int)(t * 4 + j);
                const bool lt = p < b1[nc];
                const unsigned int nb2 = lt ? b1[nc] : min(b2[nc], p);
                b1[nc] = lt ? p : b1[nc];
                b2[nc] = nb2;
            }
        }
    }
#undef LOADE
    const int slot = w * 4 + g16;
#pragma unroll
    for (int nc = 0; nc < 4; ++nc) {
        sc[slot][nc * 16 + col16][0] = b1[nc];
        sc[slot][nc * 16 + col16][1] = b2[nc];
    }
    __syncthreads();

    // ---- reduce per row: min, threshold, candidate push (incl. overflow net) ----
    if (tid < ROWS) {
        unsigned int M = 0xffffffffu;
#pragma unroll
        for (int s = 0; s < 16; ++s) M = min(M, sc[s][tid][0]);
        const unsigned int T =
            __float_as_uint(__uint_as_float(M & 0xffffffc0u) + MARGIN_ACC) | 63u;
        for (int s = 0; s < 16; ++s) {
            const unsigned int p1 = sc[s][tid][0], p2 = sc[s][tid][1];
            if (p2 <= T) {
                // scanner may have dropped a 3rd candidate <= T: enqueue its whole k-range
                const int kb = ((s >> 2) << 8) | ((s & 3) << 2);
                for (int c = 0; c < 64; ++c) {
                    int q = atomicAdd(&qcnt, 1);
                    if (q < QCAP) {
                        qk[q] = (unsigned short)(kb + ((c >> 2) << 4) + (c & 3));
                        qn[q] = (unsigned char)tid;
                    }
                }
            } else if (p1 <= T) {
                const int c = p1 & 63;
                int q = atomicAdd(&qcnt, 1);
                if (q < QCAP) {
                    qk[q] = (unsigned short)(((s >> 2) << 8) | ((c >> 2) << 4) |
                                             ((s & 3) << 2) | (c & 3));
                    qn[q] = (unsigned char)tid;
                }
            }
        }
    }
    __syncthreads();

    // ---- exact rescore (bit-exact numpy-f32), atomicMin per row ----
    const int qlen = min(qcnt, QCAP);
    for (int i = tid; i < qlen; i += 256) {
        const int r = qn[i];
        atomicMin(&rbest[r], exact_score(&zrow[r * ZPAD], lds_sn[r], emb, h_, qk[i]));
    }
    __syncthreads();

    if (qcnt > QCAP) {   // cold correctness fallback: full exact scan
        const int row = tid & 63, kq = tid >> 6;
        for (int k = kq * 256; k < kq * 256 + 256; ++k)
            atomicMin(&rbest[row], exact_score(&zrow[row * ZPAD], lds_sn[row], emb, h_, k));
        __syncthreads();
    }

    // ---- epilogue: idx, z_q gather (coalesced 256B stores), loss ----
    if (tid < ROWS) idxf[nbase + tid] = (float)(unsigned int)(rbest[tid] & 0xffffffffu);
    {
        const int I1 = (int)(rbest[l] & 0xffffffffu);   // lane = row
        const int dbase = w * 16;
        float* opb = out + (size_t)b * DSP + s0;
        float lsum = 0.f;
#pragma unroll
        for (int j = 0; j < 16; ++j) {
            const int d = dbase + j;
            float qv = emb[(size_t)I1 * DDIM + d];
            opb[(size_t)d * SPAT + l] = qv;
            float df = qv - zrow[l * ZPAD + d];
            lsum = fmaf(df, df, lsum);
        }
#pragma unroll
        for (int off = 32; off > 0; off >>= 1)
            lsum += __shfl_down(lsum, off, 64);
        if (l == 0)
            atomicAdd(loss, lsum * (1.25f / 4194304.0f));  // (beta+1)*mean
    }
}

extern "C" void kernel_launch(void* const* d_in, const int* in_sizes, int n_in,
                              void* d_out, int out_size, void* d_ws, size_t ws_size,
                              hipStream_t stream) {
    const float* z   = (const float*)d_in[0];   // [2, 64, 32, 32, 32]
    const float* emb = (const float*)d_in[1];   // [1024, 64]
    float* out  = (float*)d_out;                // z_q (4194304) | loss (1) | indices (65536)
    float* loss = out + 4194304;
    float* idxf = out + 4194305;

    float* h_   = (float*)d_ws;                 // [1024]
    float* hp_  = h_ + KDIM;                    // [1024]
    __half* ehn_ = (__half*)(hp_ + KDIM);       // [1024*64] halves

    vq_prep_e<<<KDIM / 16, 256, 0, stream>>>(emb, h_, hp_, ehn_, loss);
    vq_mfma_kernel<<<NVEC / ROWS, 256, 0, stream>>>(z, emb, ehn_, h_, hp_, out, loss, idxf);
}